// Round 9
// baseline (105.862 us; speedup 1.0000x reference)
//
#include <hip/hip_runtime.h>
#include <hip/hip_cooperative_groups.h>

namespace cg = cooperative_groups;

#define Hd 64
#define Wd 256
#define HWd 16384
#define NPTS 16384

#define F(x) __int_as_float(x)

// ---- Device port of glibc/msun flt-32 atanf (5-coefficient version) ----
__device__ __forceinline__ float fd_atanf(float x) {
    int hx = __float_as_int(x);
    int ix = hx & 0x7fffffff;
    if (ix >= 0x4c800000) {                    // |x| >= 2^26
        if (ix > 0x7f800000) return x;         // NaN
        float r = __fadd_rn(F(0x3FC90FDA), F(0x33A22168));
        return (hx > 0) ? r : -r;
    }
    int id;
    if (ix < 0x3ee00000) {                     // |x| < 0.4375
        if (ix < 0x39800000) return x;         // |x| < 2^-12
        id = -1;
    } else {
        x = F(ix);                             // fabsf
        if (ix < 0x3f980000) {                 // |x| < 1.1875
            if (ix < 0x3f300000) {             // 7/16 <= |x| < 11/16
                id = 0;
                x = __fdiv_rn(__fsub_rn(__fadd_rn(x, x), 1.0f), __fadd_rn(2.0f, x));
            } else {                           // 11/16 <= |x| < 19/16
                id = 1;
                x = __fdiv_rn(__fsub_rn(x, 1.0f), __fadd_rn(x, 1.0f));
            }
        } else {
            if (ix < 0x401c0000) {             // |x| < 2.4375
                id = 2;
                x = __fdiv_rn(__fsub_rn(x, 1.5f), __fadd_rn(1.0f, __fmul_rn(1.5f, x)));
            } else {                           // 2.4375 <= |x| < 2^26
                id = 3;
                x = __fdiv_rn(-1.0f, x);
            }
        }
    }
    // msun 5-coefficient split polynomial
    float z = __fmul_rn(x, x);
    float w = __fmul_rn(z, z);
    float s1 = __fmul_rn(z, __fadd_rn(F(0x3EAAAAA3),
                    __fmul_rn(w, __fadd_rn(F(0x3E11F50D),
                    __fmul_rn(w, F(0x3D7CAC25))))));
    float s2 = __fmul_rn(w, __fadd_rn(F(0xBE4CCA17),
                    __fmul_rn(w, F(0xBDDA1247))));
    float ss = __fadd_rn(s1, s2);
    if (id < 0) return __fsub_rn(x, __fmul_rn(x, ss));
    const float athi[4] = {F(0x3EED6338), F(0x3F490FDA), F(0x3F7B985E), F(0x3FC90FDA)};
    const float atlo[4] = {F(0x31AC3769), F(0x33222168), F(0x33140FB4), F(0x33A22168)};
    float zr = __fsub_rn(athi[id], __fsub_rn(__fsub_rn(__fmul_rn(x, ss), atlo[id]), x));
    return (hx < 0) ? -zr : zr;
}

// ---- Device port of glibc/msun flt-32 atan2f wrapper ----
__device__ __forceinline__ float fd_atan2f(float y, float x) {
    const float pi     = F(0x40490FDB);
    const float pi_lo  = F(0xB3BBBD2E);
    const float pi_o_2 = F(0x3FC90FDB);
    int hx = __float_as_int(x), ix = hx & 0x7fffffff;
    int hy = __float_as_int(y), iy = hy & 0x7fffffff;
    if (ix > 0x7f800000 || iy > 0x7f800000) return x + y;  // NaN
    if (hx == 0x3f800000) return fd_atanf(y);              // x == 1.0
    int m = ((hy >> 31) & 1) | ((hx >> 30) & 2);
    if (iy == 0) {
        switch (m) { case 0: case 1: return y; case 2: return pi; default: return -pi; }
    }
    if (ix == 0) return (hy < 0) ? -pi_o_2 : pi_o_2;
    if (ix == 0x7f800000) {
        if (iy == 0x7f800000) {
            switch (m) {
                case 0: return F(0x3F490FDB);
                case 1: return -F(0x3F490FDB);
                case 2: return __fmul_rn(3.0f, F(0x3F490FDB));
                default: return -__fmul_rn(3.0f, F(0x3F490FDB));
            }
        } else {
            switch (m) { case 0: return 0.0f; case 1: return -0.0f; case 2: return pi; default: return -pi; }
        }
    }
    if (iy == 0x7f800000) return (hy < 0) ? -pi_o_2 : pi_o_2;
    int k = (iy - ix) >> 23;      // approx exponent difference
    float z;
    if (k > 26) { z = __fadd_rn(pi_o_2, __fmul_rn(0.5f, pi_lo)); m &= 1; }
    else if (hx < 0 && k < -26) z = 0.0f;
    else z = fd_atanf(__fdiv_rn(F(iy), F(ix)));  // atanf(fabsf(y/x))
    switch (m) {
        case 0: return z;
        case 1: return -z;
        case 2: return __fsub_rn(pi, __fsub_rn(z, pi_lo));
        default: return __fsub_rn(__fsub_rn(z, pi_lo), pi);
    }
}

// One cooperative kernel: zero -> scatter -> finalize with grid-wide syncs.
// 64 blocks x 256 threads = 16384 threads, one per point / per pixel.
__global__ __launch_bounds__(256) void fused(
        const float* __restrict__ xyz,
        const float* __restrict__ angle,
        float* __restrict__ num,
        float* __restrict__ den,
        float* __restrict__ out) {
    cg::grid_group grid = cg::this_grid();

    __shared__ float s_eu[Hd], s_eu2[Hd];
    __shared__ float s_ev[Wd], s_ev2[Wd];

    int t = threadIdx.x;
    int gid = blockIdx.x * 256 + t;

    // Phase A: zero accumulators (replaces hipMemsetAsync) + load LDS tables.
    num[gid] = 0.0f;
    den[gid] = 0.0f;
    if (t < Hd) {
        float e = angle[t * Wd];          // channel 0 (elev), row t, col 0
        s_eu[t]  = e;
        s_eu2[t] = __fmul_rn(e, e);
    }
    {
        float a = angle[HWd + t];         // channel 1 (azim), row 0, col t
        s_ev[t]  = a;
        s_ev2[t] = __fmul_rn(a, a);
    }
    __syncthreads();
    grid.sync();

    // Phase B: per-point projection + frozen argmin + scatter.
    {
        float x = xyz[3 * gid + 0];
        float y = xyz[3 * gid + 1];
        float z = xyz[3 * gid + 2];

        float xx = __fmul_rn(x, x);
        float yy = __fmul_rn(y, y);
        float zz = __fmul_rn(z, z);
        float r2 = __fadd_rn(xx, yy);
        float r  = __fsqrt_rn(r2);
        float d  = __fsqrt_rn(__fadd_rn(r2, zz));

        float wgt    = expf(-2.0f * d);
        float depth1 = __fmul_rn(d, 80.0f);
        if (!(depth1 > 1.45f && depth1 < 80.0f)) wgt = 0.0f;

        if (wgt != 0.0f) {   // wgt==0 contributes exact zeros in the ref
            // Frozen: glibc msun f32 atan2 (bit-matches host libm).
            float au = fd_atan2f(z, r);
            float av = fd_atan2f(y, x);

            // f32 analytic separable-nearest center (heuristic only; the
            // exact-replica 3x3 window below absorbs +-1 ambiguity, and the
            // staircase argmin is provably within +-1 of the true nearest).
            float inv_su = __fdiv_rn((float)(Hd - 1), __fsub_rn(s_eu[Hd - 1], s_eu[0]));
            float inv_sv = __fdiv_rn((float)(Wd - 1), __fsub_rn(s_ev[Wd - 1], s_ev[0]));
            int bh = __float2int_rn(__fmul_rn(__fsub_rn(au, s_eu[0]), inv_su));
            int bw = __float2int_rn(__fmul_rn(__fsub_rn(av, s_ev[0]), inv_sv));
            bh = bh < 0 ? 0 : (bh > Hd - 1 ? Hd - 1 : bh);
            bw = bw < 0 ? 0 : (bw > Wd - 1 ? Wd - 1 : bw);

            // Frozen decision: exact f32 replica of ref's expansion-formula d2,
            // FMA-accumulated dot (Eigen GEMM), first-smallest-index tie-break.
            float asq = __fadd_rn(__fmul_rn(au, au), __fmul_rn(av, av));
            float bestd = 3.4e38f; int besti = 0x7fffffff;
            #pragma unroll
            for (int dh = -1; dh <= 1; ++dh) {
                int hh = bh + dh; hh = hh < 0 ? 0 : (hh > Hd - 1 ? Hd - 1 : hh);
                #pragma unroll
                for (int dw = -1; dw <= 1; ++dw) {
                    int ww = bw + dw; ww = ww < 0 ? 0 : (ww > Wd - 1 ? Wd - 1 : ww);
                    float gsq = __fadd_rn(s_eu2[hh], s_ev2[ww]);
                    float dot = __builtin_fmaf(av, s_ev[ww], __fmul_rn(au, s_eu[hh]));
                    float d2  = __fsub_rn(__fadd_rn(asq, gsq), __fmul_rn(2.0f, dot));
                    int idx = hh * Wd + ww;
                    if (d2 < bestd || (d2 == bestd && idx < besti)) { bestd = d2; besti = idx; }
                }
            }

            atomicAdd(&num[besti], __fmul_rn(wgt, depth1));
            atomicAdd(&den[besti], wgt);
        }
    }

    __threadfence();
    grid.sync();

    // Phase C: per-pixel finalize.
    {
        float d2d = __fdiv_rn(num[gid], __fadd_rn(den[gid], 1e-8f));
        bool valid = (d2d != 0.0f);
        float nrm = __fdiv_rn(__fsub_rn(d2d, 1.45f), 78.55f);
        out[gid]       = valid ? nrm : 1.0f;
        out[HWd + gid] = valid ? 1.0f : 0.0f;
    }
}

extern "C" void kernel_launch(void* const* d_in, const int* in_sizes, int n_in,
                              void* d_out, int out_size, void* d_ws, size_t ws_size,
                              hipStream_t stream) {
    const float* xyz   = (const float*)d_in[0];   // (1, 16384, 3)
    const float* angle = (const float*)d_in[1];   // (1, 2, 64, 256)
    float* out = (float*)d_out;                   // 32768 floats
    float* num = (float*)d_ws;
    float* den = num + HWd;

    void* args[] = {(void*)&xyz, (void*)&angle, (void*)&num, (void*)&den, (void*)&out};
    hipLaunchCooperativeKernel((void*)fused, dim3(NPTS / 256), dim3(256),
                               args, 0, stream);
}

// Round 10
// 95.299 us; speedup vs baseline: 1.1108x; 1.1108x over previous
//
#include <hip/hip_runtime.h>

#define Hd 64
#define Wd 256
#define HWd 16384
#define NPTS 16384

#define F(x) __int_as_float(x)

// ---- Device port of glibc/msun flt-32 atanf (5-coefficient version) ----
__device__ __forceinline__ float fd_atanf(float x) {
    int hx = __float_as_int(x);
    int ix = hx & 0x7fffffff;
    if (ix >= 0x4c800000) {                    // |x| >= 2^26
        if (ix > 0x7f800000) return x;         // NaN
        float r = __fadd_rn(F(0x3FC90FDA), F(0x33A22168));
        return (hx > 0) ? r : -r;
    }
    int id;
    if (ix < 0x3ee00000) {                     // |x| < 0.4375
        if (ix < 0x39800000) return x;         // |x| < 2^-12
        id = -1;
    } else {
        x = F(ix);                             // fabsf
        if (ix < 0x3f980000) {                 // |x| < 1.1875
            if (ix < 0x3f300000) {             // 7/16 <= |x| < 11/16
                id = 0;
                x = __fdiv_rn(__fsub_rn(__fadd_rn(x, x), 1.0f), __fadd_rn(2.0f, x));
            } else {                           // 11/16 <= |x| < 19/16
                id = 1;
                x = __fdiv_rn(__fsub_rn(x, 1.0f), __fadd_rn(x, 1.0f));
            }
        } else {
            if (ix < 0x401c0000) {             // |x| < 2.4375
                id = 2;
                x = __fdiv_rn(__fsub_rn(x, 1.5f), __fadd_rn(1.0f, __fmul_rn(1.5f, x)));
            } else {                           // 2.4375 <= |x| < 2^26
                id = 3;
                x = __fdiv_rn(-1.0f, x);
            }
        }
    }
    // msun 5-coefficient split polynomial
    float z = __fmul_rn(x, x);
    float w = __fmul_rn(z, z);
    float s1 = __fmul_rn(z, __fadd_rn(F(0x3EAAAAA3),
                    __fmul_rn(w, __fadd_rn(F(0x3E11F50D),
                    __fmul_rn(w, F(0x3D7CAC25))))));
    float s2 = __fmul_rn(w, __fadd_rn(F(0xBE4CCA17),
                    __fmul_rn(w, F(0xBDDA1247))));
    float ss = __fadd_rn(s1, s2);
    if (id < 0) return __fsub_rn(x, __fmul_rn(x, ss));
    const float athi[4] = {F(0x3EED6338), F(0x3F490FDA), F(0x3F7B985E), F(0x3FC90FDA)};
    const float atlo[4] = {F(0x31AC3769), F(0x33222168), F(0x33140FB4), F(0x33A22168)};
    float zr = __fsub_rn(athi[id], __fsub_rn(__fsub_rn(__fmul_rn(x, ss), atlo[id]), x));
    return (hx < 0) ? -zr : zr;
}

// ---- Device port of glibc/msun flt-32 atan2f wrapper ----
__device__ __forceinline__ float fd_atan2f(float y, float x) {
    const float pi     = F(0x40490FDB);
    const float pi_lo  = F(0xB3BBBD2E);
    const float pi_o_2 = F(0x3FC90FDB);
    int hx = __float_as_int(x), ix = hx & 0x7fffffff;
    int hy = __float_as_int(y), iy = hy & 0x7fffffff;
    if (ix > 0x7f800000 || iy > 0x7f800000) return x + y;  // NaN
    if (hx == 0x3f800000) return fd_atanf(y);              // x == 1.0
    int m = ((hy >> 31) & 1) | ((hx >> 30) & 2);
    if (iy == 0) {
        switch (m) { case 0: case 1: return y; case 2: return pi; default: return -pi; }
    }
    if (ix == 0) return (hy < 0) ? -pi_o_2 : pi_o_2;
    if (ix == 0x7f800000) {
        if (iy == 0x7f800000) {
            switch (m) {
                case 0: return F(0x3F490FDB);
                case 1: return -F(0x3F490FDB);
                case 2: return __fmul_rn(3.0f, F(0x3F490FDB));
                default: return -__fmul_rn(3.0f, F(0x3F490FDB));
            }
        } else {
            switch (m) { case 0: return 0.0f; case 1: return -0.0f; case 2: return pi; default: return -pi; }
        }
    }
    if (iy == 0x7f800000) return (hy < 0) ? -pi_o_2 : pi_o_2;
    int k = (iy - ix) >> 23;      // approx exponent difference
    float z;
    if (k > 26) { z = __fadd_rn(pi_o_2, __fmul_rn(0.5f, pi_lo)); m &= 1; }
    else if (hx < 0 && k < -26) z = 0.0f;
    else z = fd_atanf(__fdiv_rn(F(iy), F(ix)));  // atanf(fabsf(y/x))
    switch (m) {
        case 0: return z;
        case 1: return -z;
        case 2: return __fsub_rn(pi, __fsub_rn(z, pi_lo));
        default: return __fsub_rn(__fsub_rn(z, pi_lo), pi);
    }
}

// One REGULAR dispatch: scatter with device-scope atomics, then a deadlock-free
// last-block election finalizes all pixels. num/den/counter pre-zeroed by the
// tiny memset dispatch. 64 blocks x 256 threads.
__global__ __launch_bounds__(256) void fused(
        const float* __restrict__ xyz,
        const float* __restrict__ angle,
        float* __restrict__ num,
        float* __restrict__ den,
        unsigned int* __restrict__ counter,
        float* __restrict__ out) {
    __shared__ float s_eu[Hd], s_eu2[Hd];
    __shared__ float s_ev[Wd], s_ev2[Wd];
    __shared__ int s_last;

    int t = threadIdx.x;
    int gid = blockIdx.x * 256 + t;

    if (t < Hd) {
        float e = angle[t * Wd];          // channel 0 (elev), row t, col 0
        s_eu[t]  = e;
        s_eu2[t] = __fmul_rn(e, e);
    }
    {
        float a = angle[HWd + t];         // channel 1 (azim), row 0, col t
        s_ev[t]  = a;
        s_ev2[t] = __fmul_rn(a, a);
    }
    __syncthreads();

    // ---- Per-point projection + frozen argmin + scatter ----
    {
        float x = xyz[3 * gid + 0];
        float y = xyz[3 * gid + 1];
        float z = xyz[3 * gid + 2];

        float xx = __fmul_rn(x, x);
        float yy = __fmul_rn(y, y);
        float zz = __fmul_rn(z, z);
        float r2 = __fadd_rn(xx, yy);
        float r  = __fsqrt_rn(r2);
        float d  = __fsqrt_rn(__fadd_rn(r2, zz));

        float wgt    = expf(-2.0f * d);
        float depth1 = __fmul_rn(d, 80.0f);
        if (!(depth1 > 1.45f && depth1 < 80.0f)) wgt = 0.0f;

        if (wgt != 0.0f) {   // wgt==0 contributes exact zeros in the ref
            // Frozen: glibc msun f32 atan2 (bit-matches host libm).
            float au = fd_atan2f(z, r);
            float av = fd_atan2f(y, x);

            // Analytic separable-nearest center (heuristic; the exact-replica
            // 3x3 window below absorbs +-1 ambiguity).
            float inv_su = __fdiv_rn((float)(Hd - 1), __fsub_rn(s_eu[Hd - 1], s_eu[0]));
            float inv_sv = __fdiv_rn((float)(Wd - 1), __fsub_rn(s_ev[Wd - 1], s_ev[0]));
            int bh = __float2int_rn(__fmul_rn(__fsub_rn(au, s_eu[0]), inv_su));
            int bw = __float2int_rn(__fmul_rn(__fsub_rn(av, s_ev[0]), inv_sv));
            bh = bh < 0 ? 0 : (bh > Hd - 1 ? Hd - 1 : bh);
            bw = bw < 0 ? 0 : (bw > Wd - 1 ? Wd - 1 : bw);

            // Frozen decision: exact f32 replica of ref's expansion-formula d2,
            // FMA-accumulated dot (Eigen GEMM), first-smallest-index tie-break.
            float asq = __fadd_rn(__fmul_rn(au, au), __fmul_rn(av, av));
            float bestd = 3.4e38f; int besti = 0x7fffffff;
            #pragma unroll
            for (int dh = -1; dh <= 1; ++dh) {
                int hh = bh + dh; hh = hh < 0 ? 0 : (hh > Hd - 1 ? Hd - 1 : hh);
                #pragma unroll
                for (int dw = -1; dw <= 1; ++dw) {
                    int ww = bw + dw; ww = ww < 0 ? 0 : (ww > Wd - 1 ? Wd - 1 : ww);
                    float gsq = __fadd_rn(s_eu2[hh], s_ev2[ww]);
                    float dot = __builtin_fmaf(av, s_ev[ww], __fmul_rn(au, s_eu[hh]));
                    float d2  = __fsub_rn(__fadd_rn(asq, gsq), __fmul_rn(2.0f, dot));
                    int idx = hh * Wd + ww;
                    if (d2 < bestd || (d2 == bestd && idx < besti)) { bestd = d2; besti = idx; }
                }
            }

            atomicAdd(&num[besti], __fmul_rn(wgt, depth1));  // device scope
            atomicAdd(&den[besti], wgt);
        }
    }

    // ---- Last-block election (no spin, deadlock-free) ----
    __syncthreads();            // block's atomics all issued
    __threadfence();            // release: drain to device scope
    if (t == 0) {
        unsigned int old = __hip_atomic_fetch_add(counter, 1u, __ATOMIC_ACQ_REL,
                                                  __HIP_MEMORY_SCOPE_AGENT);
        s_last = (old == 63);
    }
    __syncthreads();

    if (s_last) {
        __threadfence();        // acquire: see all other blocks' atomics
        #pragma unroll 4
        for (int i = t; i < HWd; i += 256) {
            // Agent-scope atomic loads dodge stale per-XCD L1/L2 lines.
            float nv = __hip_atomic_load(&num[i], __ATOMIC_RELAXED, __HIP_MEMORY_SCOPE_AGENT);
            float dv = __hip_atomic_load(&den[i], __ATOMIC_RELAXED, __HIP_MEMORY_SCOPE_AGENT);
            float d2d = __fdiv_rn(nv, __fadd_rn(dv, 1e-8f));
            bool valid = (d2d != 0.0f);
            float nrm = __fdiv_rn(__fsub_rn(d2d, 1.45f), 78.55f);
            out[i]       = valid ? nrm : 1.0f;
            out[HWd + i] = valid ? 1.0f : 0.0f;
        }
    }
}

extern "C" void kernel_launch(void* const* d_in, const int* in_sizes, int n_in,
                              void* d_out, int out_size, void* d_ws, size_t ws_size,
                              hipStream_t stream) {
    const float* xyz   = (const float*)d_in[0];   // (1, 16384, 3)
    const float* angle = (const float*)d_in[1];   // (1, 2, 64, 256)
    float* out = (float*)d_out;                   // 32768 floats
    float* num = (float*)d_ws;                    // HW floats
    float* den = num + HWd;                       // HW floats
    unsigned int* counter = (unsigned int*)(den + HWd);

    // Zero num, den, and the election counter in one tiny fill.
    hipMemsetAsync(d_ws, 0, (2 * HWd + 4) * sizeof(float), stream);
    fused<<<NPTS / 256, 256, 0, stream>>>(xyz, angle, num, den, counter, out);
}

// Round 11
// 71.147 us; speedup vs baseline: 1.4879x; 1.3395x over previous
//
#include <hip/hip_runtime.h>

#define Hd 64
#define Wd 256
#define HWd 16384
#define NPTS 16384
#define NB 16            // scatter blocks
#define PPT 4            // points per thread (NB*256*PPT == NPTS)
#define HHW 8192         // half-histogram entries (32 KB LDS)

#define F(x) __int_as_float(x)

// ---- Device port of glibc/msun flt-32 atanf (5-coefficient version) ----
__device__ __forceinline__ float fd_atanf(float x) {
    int hx = __float_as_int(x);
    int ix = hx & 0x7fffffff;
    if (ix >= 0x4c800000) {                    // |x| >= 2^26
        if (ix > 0x7f800000) return x;         // NaN
        float r = __fadd_rn(F(0x3FC90FDA), F(0x33A22168));
        return (hx > 0) ? r : -r;
    }
    int id;
    if (ix < 0x3ee00000) {                     // |x| < 0.4375
        if (ix < 0x39800000) return x;         // |x| < 2^-12
        id = -1;
    } else {
        x = F(ix);                             // fabsf
        if (ix < 0x3f980000) {                 // |x| < 1.1875
            if (ix < 0x3f300000) {             // 7/16 <= |x| < 11/16
                id = 0;
                x = __fdiv_rn(__fsub_rn(__fadd_rn(x, x), 1.0f), __fadd_rn(2.0f, x));
            } else {                           // 11/16 <= |x| < 19/16
                id = 1;
                x = __fdiv_rn(__fsub_rn(x, 1.0f), __fadd_rn(x, 1.0f));
            }
        } else {
            if (ix < 0x401c0000) {             // |x| < 2.4375
                id = 2;
                x = __fdiv_rn(__fsub_rn(x, 1.5f), __fadd_rn(1.0f, __fmul_rn(1.5f, x)));
            } else {                           // 2.4375 <= |x| < 2^26
                id = 3;
                x = __fdiv_rn(-1.0f, x);
            }
        }
    }
    // msun 5-coefficient split polynomial
    float z = __fmul_rn(x, x);
    float w = __fmul_rn(z, z);
    float s1 = __fmul_rn(z, __fadd_rn(F(0x3EAAAAA3),
                    __fmul_rn(w, __fadd_rn(F(0x3E11F50D),
                    __fmul_rn(w, F(0x3D7CAC25))))));
    float s2 = __fmul_rn(w, __fadd_rn(F(0xBE4CCA17),
                    __fmul_rn(w, F(0xBDDA1247))));
    float ss = __fadd_rn(s1, s2);
    if (id < 0) return __fsub_rn(x, __fmul_rn(x, ss));
    const float athi[4] = {F(0x3EED6338), F(0x3F490FDA), F(0x3F7B985E), F(0x3FC90FDA)};
    const float atlo[4] = {F(0x31AC3769), F(0x33222168), F(0x33140FB4), F(0x33A22168)};
    float zr = __fsub_rn(athi[id], __fsub_rn(__fsub_rn(__fmul_rn(x, ss), atlo[id]), x));
    return (hx < 0) ? -zr : zr;
}

// ---- Device port of glibc/msun flt-32 atan2f wrapper ----
__device__ __forceinline__ float fd_atan2f(float y, float x) {
    const float pi     = F(0x40490FDB);
    const float pi_lo  = F(0xB3BBBD2E);
    const float pi_o_2 = F(0x3FC90FDB);
    int hx = __float_as_int(x), ix = hx & 0x7fffffff;
    int hy = __float_as_int(y), iy = hy & 0x7fffffff;
    if (ix > 0x7f800000 || iy > 0x7f800000) return x + y;  // NaN
    if (hx == 0x3f800000) return fd_atanf(y);              // x == 1.0
    int m = ((hy >> 31) & 1) | ((hx >> 30) & 2);
    if (iy == 0) {
        switch (m) { case 0: case 1: return y; case 2: return pi; default: return -pi; }
    }
    if (ix == 0) return (hy < 0) ? -pi_o_2 : pi_o_2;
    if (ix == 0x7f800000) {
        if (iy == 0x7f800000) {
            switch (m) {
                case 0: return F(0x3F490FDB);
                case 1: return -F(0x3F490FDB);
                case 2: return __fmul_rn(3.0f, F(0x3F490FDB));
                default: return -__fmul_rn(3.0f, F(0x3F490FDB));
            }
        } else {
            switch (m) { case 0: return 0.0f; case 1: return -0.0f; case 2: return pi; default: return -pi; }
        }
    }
    if (iy == 0x7f800000) return (hy < 0) ? -pi_o_2 : pi_o_2;
    int k = (iy - ix) >> 23;      // approx exponent difference
    float z;
    if (k > 26) { z = __fadd_rn(pi_o_2, __fmul_rn(0.5f, pi_lo)); m &= 1; }
    else if (hx < 0 && k < -26) z = 0.0f;
    else z = fd_atanf(__fdiv_rn(F(iy), F(ix)));  // atanf(fabsf(y/x))
    switch (m) {
        case 0: return z;
        case 1: return -z;
        case 2: return __fsub_rn(pi, __fsub_rn(z, pi_lo));
        default: return __fsub_rn(__fsub_rn(z, pi_lo), pi);
    }
}

// Kernel 1: 16 blocks x 256 threads, 4 points/thread. Frozen per-point
// decision; accumulate into a private 32KB LDS half-histogram (two halves,
// num then den), stream full partial slices (zeros included) to d_ws.
// No global atomics, no pre-zeroed global state -> no memset dispatch.
__global__ __launch_bounds__(256) void scatter_partials(
        const float* __restrict__ xyz,
        const float* __restrict__ angle,
        float* __restrict__ part) {   // layout: [num: NB][HWd] then [den: NB][HWd]
    __shared__ float s_eu[Hd], s_eu2[Hd];
    __shared__ float s_ev[Wd], s_ev2[Wd];
    __shared__ float hist[HHW];

    int t = threadIdx.x, b = blockIdx.x;
    if (t < Hd) {
        float e = angle[t * Wd];          // channel 0 (elev), row t, col 0
        s_eu[t]  = e;
        s_eu2[t] = __fmul_rn(e, e);
    }
    {
        float a = angle[HWd + t];         // channel 1 (azim), row 0, col t
        s_ev[t]  = a;
        s_ev2[t] = __fmul_rn(a, a);
    }
    __syncthreads();

    int   besti[PPT];
    float addn[PPT], addd[PPT];

    #pragma unroll
    for (int k = 0; k < PPT; ++k) {
        int n = b * (256 * PPT) + k * 256 + t;   // coalesced per k
        float x = xyz[3 * n + 0];
        float y = xyz[3 * n + 1];
        float z = xyz[3 * n + 2];

        float xx = __fmul_rn(x, x);
        float yy = __fmul_rn(y, y);
        float zz = __fmul_rn(z, z);
        float r2 = __fadd_rn(xx, yy);
        float r  = __fsqrt_rn(r2);
        float d  = __fsqrt_rn(__fadd_rn(r2, zz));

        float wgt    = expf(-2.0f * d);
        float depth1 = __fmul_rn(d, 80.0f);
        if (!(depth1 > 1.45f && depth1 < 80.0f)) wgt = 0.0f;

        besti[k] = -1;
        addn[k] = 0.0f; addd[k] = 0.0f;
        if (wgt != 0.0f) {   // wgt==0 contributes exact zeros in the ref
            // Frozen: glibc msun f32 atan2 (bit-matches host libm).
            float au = fd_atan2f(z, r);
            float av = fd_atan2f(y, x);

            // Analytic separable-nearest center (heuristic; exact-replica 3x3
            // window below absorbs +-1 ambiguity).
            float inv_su = __fdiv_rn((float)(Hd - 1), __fsub_rn(s_eu[Hd - 1], s_eu[0]));
            float inv_sv = __fdiv_rn((float)(Wd - 1), __fsub_rn(s_ev[Wd - 1], s_ev[0]));
            int bh = __float2int_rn(__fmul_rn(__fsub_rn(au, s_eu[0]), inv_su));
            int bw = __float2int_rn(__fmul_rn(__fsub_rn(av, s_ev[0]), inv_sv));
            bh = bh < 0 ? 0 : (bh > Hd - 1 ? Hd - 1 : bh);
            bw = bw < 0 ? 0 : (bw > Wd - 1 ? Wd - 1 : bw);

            // Frozen decision: exact f32 replica of ref's expansion-formula d2,
            // FMA-accumulated dot (Eigen GEMM), first-smallest-index tie-break.
            float asq = __fadd_rn(__fmul_rn(au, au), __fmul_rn(av, av));
            float bestd = 3.4e38f; int bi = 0x7fffffff;
            #pragma unroll
            for (int dh = -1; dh <= 1; ++dh) {
                int hh = bh + dh; hh = hh < 0 ? 0 : (hh > Hd - 1 ? Hd - 1 : hh);
                #pragma unroll
                for (int dw = -1; dw <= 1; ++dw) {
                    int ww = bw + dw; ww = ww < 0 ? 0 : (ww > Wd - 1 ? Wd - 1 : ww);
                    float gsq = __fadd_rn(s_eu2[hh], s_ev2[ww]);
                    float dot = __builtin_fmaf(av, s_ev[ww], __fmul_rn(au, s_eu[hh]));
                    float d2  = __fsub_rn(__fadd_rn(asq, gsq), __fmul_rn(2.0f, dot));
                    int idx = hh * Wd + ww;
                    if (d2 < bestd || (d2 == bestd && idx < bi)) { bestd = d2; bi = idx; }
                }
            }
            besti[k] = bi;
            addn[k]  = __fmul_rn(wgt, depth1);
            addd[k]  = wgt;
        }
    }

    float* pn = part + b * HWd;             // this block's num partial slice
    float* pd = part + (NB + b) * HWd;      // this block's den partial slice
    const float4 z4 = make_float4(0.0f, 0.0f, 0.0f, 0.0f);

    #pragma unroll
    for (int half = 0; half < 2; ++half) {
        int lo = half * HHW;
        // --- num, this half ---
        __syncthreads();                               // prior dump reads done
        for (int j = t; j < HHW / 4; j += 256) ((float4*)hist)[j] = z4;
        __syncthreads();
        #pragma unroll
        for (int k = 0; k < PPT; ++k)
            if (besti[k] >= lo && besti[k] < lo + HHW)
                atomicAdd(&hist[besti[k] - lo], addn[k]);
        __syncthreads();
        for (int j = t; j < HHW / 4; j += 256) ((float4*)(pn + lo))[j] = ((float4*)hist)[j];
        // --- den, this half ---
        __syncthreads();
        for (int j = t; j < HHW / 4; j += 256) ((float4*)hist)[j] = z4;
        __syncthreads();
        #pragma unroll
        for (int k = 0; k < PPT; ++k)
            if (besti[k] >= lo && besti[k] < lo + HHW)
                atomicAdd(&hist[besti[k] - lo], addd[k]);
        __syncthreads();
        for (int j = t; j < HHW / 4; j += 256) ((float4*)(pd + lo))[j] = ((float4*)hist)[j];
    }
}

// Kernel 2: sum the 16 partials per pixel (ascending block order) + epilogue.
__global__ __launch_bounds__(256) void finalize_sum(
        const float* __restrict__ part,
        float* __restrict__ out) {
    int i = blockIdx.x * 256 + threadIdx.x;
    float n = 0.0f, d = 0.0f;
    #pragma unroll
    for (int b = 0; b < NB; ++b) {
        n = __fadd_rn(n, part[b * HWd + i]);
        d = __fadd_rn(d, part[(NB + b) * HWd + i]);
    }
    float d2d = __fdiv_rn(n, __fadd_rn(d, 1e-8f));
    bool valid = (d2d != 0.0f);
    float nrm = __fdiv_rn(__fsub_rn(d2d, 1.45f), 78.55f);
    out[i]       = valid ? nrm : 1.0f;
    out[HWd + i] = valid ? 1.0f : 0.0f;
}

extern "C" void kernel_launch(void* const* d_in, const int* in_sizes, int n_in,
                              void* d_out, int out_size, void* d_ws, size_t ws_size,
                              hipStream_t stream) {
    const float* xyz   = (const float*)d_in[0];   // (1, 16384, 3)
    const float* angle = (const float*)d_in[1];   // (1, 2, 64, 256)
    float* out  = (float*)d_out;                  // 32768 floats
    float* part = (float*)d_ws;                   // 2 * NB * HWd floats = 2 MB

    scatter_partials<<<NB, 256, 0, stream>>>(xyz, angle, part);
    finalize_sum<<<HWd / 256, 256, 0, stream>>>(part, out);
}